// Round 1
// baseline (4754.748 us; speedup 1.0000x reference)
//
#include <hip/hip_runtime.h>
#include <math.h>

#define N_NODES 200000
#define H_CH    128
#define NNZ_E   3200000
#define K_DEG   15

// ---------- softmax over 16 logits ----------
__global__ void softmax_k(const float* __restrict__ logits, float* __restrict__ w) {
    if (threadIdx.x == 0) {
        float m = -1e30f;
        for (int i = 0; i <= K_DEG; ++i) m = fmaxf(m, logits[i]);
        float e[K_DEG + 1];
        float s = 0.f;
        for (int i = 0; i <= K_DEG; ++i) { e[i] = expf(logits[i] - m); s += e[i]; }
        float inv = 1.0f / s;
        for (int i = 0; i <= K_DEG; ++i) w[i] = e[i] * inv;
    }
}

// ---------- CSR build: histogram ----------
__global__ void hist_k(const int* __restrict__ row, int* __restrict__ counts, int nnz) {
    int i = blockIdx.x * blockDim.x + threadIdx.x;
    if (i < nnz) atomicAdd(&counts[row[i]], 1);
}

// ---------- CSR build: hierarchical exclusive scan ----------
// tile = 256 threads * 8 items = 2048
__global__ void scan1_k(const int* __restrict__ counts, int* __restrict__ out,
                        int* __restrict__ partials, int n) {
    __shared__ int sm[256];
    int tbase = blockIdx.x * 2048 + threadIdx.x * 8;
    int v[8];
    int tsum = 0;
#pragma unroll
    for (int j = 0; j < 8; ++j) {
        int i = tbase + j;
        int c = (i < n) ? counts[i] : 0;
        v[j] = tsum;            // thread-local exclusive prefix
        tsum += c;
    }
    sm[threadIdx.x] = tsum;
    __syncthreads();
    int incl = tsum;
    for (int off = 1; off < 256; off <<= 1) {
        int t = (threadIdx.x >= (unsigned)off) ? sm[threadIdx.x - off] : 0;
        __syncthreads();
        incl += t;
        sm[threadIdx.x] = incl;
        __syncthreads();
    }
    int texcl = incl - tsum;
    if (threadIdx.x == 255) partials[blockIdx.x] = incl;
#pragma unroll
    for (int j = 0; j < 8; ++j) {
        int i = tbase + j;
        if (i < n) out[i] = texcl + v[j];
    }
}

__global__ void scan2_k(int* partials, int nb, int* row_ptr, int n, int total) {
    __shared__ int sm[128];
    int v = (threadIdx.x < (unsigned)nb) ? partials[threadIdx.x] : 0;
    sm[threadIdx.x] = v;
    __syncthreads();
    int incl = v;
    for (int off = 1; off < 128; off <<= 1) {
        int t = (threadIdx.x >= (unsigned)off) ? sm[threadIdx.x - off] : 0;
        __syncthreads();
        incl += t;
        sm[threadIdx.x] = incl;
        __syncthreads();
    }
    if (threadIdx.x < (unsigned)nb) partials[threadIdx.x] = incl - v;   // exclusive
    if (threadIdx.x == 0) row_ptr[n] = total;
}

__global__ void scan3_k(int* __restrict__ row_ptr, const int* __restrict__ partials,
                        int* __restrict__ fill, int n) {
    int off = partials[blockIdx.x];
    int tbase = blockIdx.x * 2048 + threadIdx.x * 8;
#pragma unroll
    for (int j = 0; j < 8; ++j) {
        int i = tbase + j;
        if (i < n) {
            int v = row_ptr[i] + off;
            row_ptr[i] = v;
            fill[i] = v;
        }
    }
}

// ---------- CSR build: scatter ----------
__global__ void scatter_k(const int* __restrict__ row, const int* __restrict__ col,
                          const float* __restrict__ vals, int* __restrict__ fill,
                          int* __restrict__ ccol, float* __restrict__ cval, int nnz) {
    int i = blockIdx.x * blockDim.x + threadIdx.x;
    if (i < nnz) {
        int r = row[i];
        int p = atomicAdd(&fill[r], 1);
        ccol[p] = col[i];
        cval[p] = vals[i];
    }
}

// ---------- first fused kernel: S = spmm(x); T1 = S - x;
//            out = -(w0*x + w1*T1) + alpha*(x - 0.5*S) ----------
__global__ __launch_bounds__(256) void first_k(
    const int* __restrict__ rp, const int* __restrict__ ccol, const float* __restrict__ cval,
    const float* __restrict__ x, float* __restrict__ T1buf, float* __restrict__ out,
    const float* __restrict__ w, const float* __restrict__ alpha_p) {
    int wid = blockIdx.x * 4 + (threadIdx.x >> 6);
    int r = __builtin_amdgcn_readfirstlane(wid);
    if (r >= N_NODES) return;
    int lane = threadIdx.x & 63;
    const float* base = x + lane * 2;
    int e0 = rp[r], e1 = rp[r + 1];
    float ax = 0.f, ay = 0.f, bx = 0.f, by = 0.f;
    int e = e0;
    for (; e + 2 <= e1; e += 2) {
        int c0 = ccol[e], c1 = ccol[e + 1];
        float v0 = cval[e], v1 = cval[e + 1];
        float2 s0 = *(const float2*)(base + (size_t)c0 * H_CH);
        float2 s1 = *(const float2*)(base + (size_t)c1 * H_CH);
        ax = fmaf(v0, s0.x, ax); ay = fmaf(v0, s0.y, ay);
        bx = fmaf(v1, s1.x, bx); by = fmaf(v1, s1.y, by);
    }
    if (e < e1) {
        int c0 = ccol[e];
        float v0 = cval[e];
        float2 s0 = *(const float2*)(base + (size_t)c0 * H_CH);
        ax = fmaf(v0, s0.x, ax); ay = fmaf(v0, s0.y, ay);
    }
    float sx = ax + bx, sy = ay + by;
    size_t idx = (size_t)r * H_CH + lane * 2;
    float2 xr = *(const float2*)(x + idx);
    float w0 = w[0], w1 = w[1], al = alpha_p[0];
    float t1x = sx - xr.x, t1y = sy - xr.y;
    float ox = -(w0 * xr.x + w1 * t1x) + al * (xr.x - 0.5f * sx);
    float oy = -(w0 * xr.y + w1 * t1y) + al * (xr.y - 0.5f * sy);
    float2 t1v; t1v.x = t1x; t1v.y = t1y;
    float2 ov;  ov.x = ox;   ov.y = oy;
    *(float2*)(T1buf + idx) = t1v;
    *(float2*)(out + idx) = ov;
}

// ---------- Chebyshev step: y = spmm(Tcur); Tn = 2*(y - Tcur) - Tprev;
//            out -= w[k]*Tn; Tnext (may alias Tprev) = Tn ----------
__global__ __launch_bounds__(256) void cheb_k(
    const int* __restrict__ rp, const int* __restrict__ ccol, const float* __restrict__ cval,
    const float* __restrict__ Tcur, const float* Tprev, float* Tnext,
    float* __restrict__ out, const float* __restrict__ w, int k) {
    int wid = blockIdx.x * 4 + (threadIdx.x >> 6);
    int r = __builtin_amdgcn_readfirstlane(wid);
    if (r >= N_NODES) return;
    int lane = threadIdx.x & 63;
    const float* base = Tcur + lane * 2;
    int e0 = rp[r], e1 = rp[r + 1];
    float ax = 0.f, ay = 0.f, bx = 0.f, by = 0.f;
    int e = e0;
    for (; e + 2 <= e1; e += 2) {
        int c0 = ccol[e], c1 = ccol[e + 1];
        float v0 = cval[e], v1 = cval[e + 1];
        float2 s0 = *(const float2*)(base + (size_t)c0 * H_CH);
        float2 s1 = *(const float2*)(base + (size_t)c1 * H_CH);
        ax = fmaf(v0, s0.x, ax); ay = fmaf(v0, s0.y, ay);
        bx = fmaf(v1, s1.x, bx); by = fmaf(v1, s1.y, by);
    }
    if (e < e1) {
        int c0 = ccol[e];
        float v0 = cval[e];
        float2 s0 = *(const float2*)(base + (size_t)c0 * H_CH);
        ax = fmaf(v0, s0.x, ax); ay = fmaf(v0, s0.y, ay);
    }
    float sx = ax + bx, sy = ay + by;
    size_t idx = (size_t)r * H_CH + lane * 2;
    float2 tc = *(const float2*)(Tcur + idx);
    float2 tp = *(const float2*)(Tprev + idx);
    float wk = w[k];
    float tnx = 2.0f * (sx - tc.x) - tp.x;
    float tny = 2.0f * (sy - tc.y) - tp.y;
    float2 ov = *(const float2*)(out + idx);
    ov.x -= wk * tnx;
    ov.y -= wk * tny;
    *(float2*)(out + idx) = ov;
    float2 tn; tn.x = tnx; tn.y = tny;
    *(float2*)(Tnext + idx) = tn;
}

extern "C" void kernel_launch(void* const* d_in, const int* in_sizes, int n_in,
                              void* d_out, int out_size, void* d_ws, size_t ws_size,
                              hipStream_t stream) {
    const float* x      = (const float*)d_in[0];
    const float* vals   = (const float*)d_in[1];
    const float* logits = (const float*)d_in[2];
    const float* alpha  = (const float*)d_in[3];
    const int*   erow   = (const int*)d_in[4];
    const int*   ecol   = (const int*)d_in[5];
    float* out = (float*)d_out;

    const size_t NH = (size_t)N_NODES * H_CH;
    float* bufA    = (float*)d_ws;
    float* bufB    = bufA + NH;
    int*   csr_col = (int*)(bufB + NH);
    float* csr_val = (float*)(csr_col + NNZ_E);
    int*   row_ptr = (int*)(csr_val + NNZ_E);      // N+1
    int*   counts  = row_ptr + (N_NODES + 1);
    int*   fill    = counts + N_NODES;
    int*   partials= fill + N_NODES;               // 128 entries
    float* w_buf   = (float*)(partials + 128);     // 16 entries

    hipMemsetAsync(counts, 0, N_NODES * sizeof(int), stream);
    softmax_k<<<1, 64, 0, stream>>>(logits, w_buf);
    hist_k<<<(NNZ_E + 255) / 256, 256, 0, stream>>>(erow, counts, NNZ_E);

    const int TILE = 2048;
    int nblk = (N_NODES + TILE - 1) / TILE;        // 98
    scan1_k<<<nblk, 256, 0, stream>>>(counts, row_ptr, partials, N_NODES);
    scan2_k<<<1, 128, 0, stream>>>(partials, nblk, row_ptr, N_NODES, NNZ_E);
    scan3_k<<<nblk, 256, 0, stream>>>(row_ptr, partials, fill, N_NODES);
    scatter_k<<<(NNZ_E + 255) / 256, 256, 0, stream>>>(erow, ecol, vals, fill,
                                                       csr_col, csr_val, NNZ_E);

    int grid = (N_NODES + 3) / 4;                  // 4 waves (rows) per 256-thread block
    first_k<<<grid, 256, 0, stream>>>(row_ptr, csr_col, csr_val, x, bufB, out, w_buf, alpha);

    // k = 2: Tcur = T1 (bufB), Tprev = T0 = x, Tnext -> bufA
    cheb_k<<<grid, 256, 0, stream>>>(row_ptr, csr_col, csr_val, bufB, x, bufA, out, w_buf, 2);

    // k = 3..15: ping-pong; Tnext aliases Tprev (read-before-write per thread)
    float* Tcur = bufA;
    float* Tprev = bufB;
    for (int k = 3; k <= K_DEG; ++k) {
        cheb_k<<<grid, 256, 0, stream>>>(row_ptr, csr_col, csr_val, Tcur, Tprev, Tprev,
                                         out, w_buf, k);
        float* t = Tcur; Tcur = Tprev; Tprev = t;
    }
}

// Round 2
// 4703.174 us; speedup vs baseline: 1.0110x; 1.0110x over previous
//
#include <hip/hip_runtime.h>
#include <math.h>

#define N_NODES 200000
#define H_CH    128
#define GRP     64          // channel group width (2 groups of 64)
#define NNZ_E   3200000
#define K_DEG   15

// ---------- softmax over 16 logits ----------
__global__ void softmax_k(const float* __restrict__ logits, float* __restrict__ w) {
    if (threadIdx.x == 0) {
        float m = -1e30f;
        for (int i = 0; i <= K_DEG; ++i) m = fmaxf(m, logits[i]);
        float e[K_DEG + 1];
        float s = 0.f;
        for (int i = 0; i <= K_DEG; ++i) { e[i] = expf(logits[i] - m); s += e[i]; }
        float inv = 1.0f / s;
        for (int i = 0; i <= K_DEG; ++i) w[i] = e[i] * inv;
    }
}

// ---------- CSR build: histogram ----------
__global__ void hist_k(const int* __restrict__ row, int* __restrict__ counts, int nnz) {
    int i = blockIdx.x * blockDim.x + threadIdx.x;
    if (i < nnz) atomicAdd(&counts[row[i]], 1);
}

// ---------- CSR build: hierarchical exclusive scan (tile = 2048) ----------
__global__ void scan1_k(const int* __restrict__ counts, int* __restrict__ out,
                        int* __restrict__ partials, int n) {
    __shared__ int sm[256];
    int tbase = blockIdx.x * 2048 + threadIdx.x * 8;
    int v[8];
    int tsum = 0;
#pragma unroll
    for (int j = 0; j < 8; ++j) {
        int i = tbase + j;
        int c = (i < n) ? counts[i] : 0;
        v[j] = tsum;
        tsum += c;
    }
    sm[threadIdx.x] = tsum;
    __syncthreads();
    int incl = tsum;
    for (int off = 1; off < 256; off <<= 1) {
        int t = (threadIdx.x >= (unsigned)off) ? sm[threadIdx.x - off] : 0;
        __syncthreads();
        incl += t;
        sm[threadIdx.x] = incl;
        __syncthreads();
    }
    int texcl = incl - tsum;
    if (threadIdx.x == 255) partials[blockIdx.x] = incl;
#pragma unroll
    for (int j = 0; j < 8; ++j) {
        int i = tbase + j;
        if (i < n) out[i] = texcl + v[j];
    }
}

__global__ void scan2_k(int* partials, int nb, int* row_ptr, int n, int total) {
    __shared__ int sm[128];
    int v = (threadIdx.x < (unsigned)nb) ? partials[threadIdx.x] : 0;
    sm[threadIdx.x] = v;
    __syncthreads();
    int incl = v;
    for (int off = 1; off < 128; off <<= 1) {
        int t = (threadIdx.x >= (unsigned)off) ? sm[threadIdx.x - off] : 0;
        __syncthreads();
        incl += t;
        sm[threadIdx.x] = incl;
        __syncthreads();
    }
    if (threadIdx.x < (unsigned)nb) partials[threadIdx.x] = incl - v;
    if (threadIdx.x == 0) row_ptr[n] = total;
}

__global__ void scan3_k(int* __restrict__ row_ptr, const int* __restrict__ partials,
                        int* __restrict__ fill, int n) {
    int off = partials[blockIdx.x];
    int tbase = blockIdx.x * 2048 + threadIdx.x * 8;
#pragma unroll
    for (int j = 0; j < 8; ++j) {
        int i = tbase + j;
        if (i < n) {
            int v = row_ptr[i] + off;
            row_ptr[i] = v;
            fill[i] = v;
        }
    }
}

// ---------- CSR build: scatter (packed col+val int2) ----------
__global__ void scatter_k(const int* __restrict__ row, const int* __restrict__ col,
                          const float* __restrict__ vals, int* __restrict__ fill,
                          int2* __restrict__ csr, int nnz) {
    int i = blockIdx.x * blockDim.x + threadIdx.x;
    if (i < nnz) {
        int r = row[i];
        int p = atomicAdd(&fill[r], 1);
        int2 cv;
        cv.x = col[i];
        cv.y = __float_as_int(vals[i]);
        csr[p] = cv;
    }
}

// ---------- first fused kernel (per 64-ch group) ----------
// S = spmm(x_g); T1_g = S - x_g (compact);
// out_g = -(w0*x_g + w1*T1_g) + alpha*(x_g - 0.5*S)
__global__ __launch_bounds__(256) void first_k(
    const int* __restrict__ rp, const int2* __restrict__ csr,
    const float* __restrict__ x, float* __restrict__ T1g, float* __restrict__ out,
    const float* __restrict__ w, const float* __restrict__ alpha_p, int goff) {
    int wid = blockIdx.x * 4 + (threadIdx.x >> 6);
    int r = __builtin_amdgcn_readfirstlane(wid);
    if (r >= N_NODES) return;
    int lane = threadIdx.x & 63;
    const float* base = x + goff + lane;      // gather x[col*128 + goff + lane]
    int e0 = rp[r], e1 = rp[r + 1];
    float a0 = 0.f, a1 = 0.f, a2 = 0.f, a3 = 0.f;
    int e = e0;
    for (; e + 4 <= e1; e += 4) {
        int2 cv0 = csr[e], cv1 = csr[e + 1], cv2 = csr[e + 2], cv3 = csr[e + 3];
        a0 = fmaf(__int_as_float(cv0.y), base[(size_t)cv0.x * H_CH], a0);
        a1 = fmaf(__int_as_float(cv1.y), base[(size_t)cv1.x * H_CH], a1);
        a2 = fmaf(__int_as_float(cv2.y), base[(size_t)cv2.x * H_CH], a2);
        a3 = fmaf(__int_as_float(cv3.y), base[(size_t)cv3.x * H_CH], a3);
    }
    for (; e < e1; ++e) {
        int2 cv = csr[e];
        a0 = fmaf(__int_as_float(cv.y), base[(size_t)cv.x * H_CH], a0);
    }
    float s = (a0 + a1) + (a2 + a3);
    size_t idxg = (size_t)r * GRP + lane;
    size_t idxf = (size_t)r * H_CH + goff + lane;
    float xr = x[idxf];
    float w0 = w[0], w1 = w[1], al = alpha_p[0];
    float t1 = s - xr;
    float o = -(w0 * xr + w1 * t1) + al * (xr - 0.5f * s);
    T1g[idxg] = t1;
    out[idxf] = o;
}

// ---------- Chebyshev step (per 64-ch group) ----------
// y = spmm(Tcur); Tn = 2*(y - Tcur) - Tprev; out -= w[k]*Tn; Tnext = Tn
// TprevBase has row stride tprevStride (128 when Tprev = x slice at k=2, else 64)
__global__ __launch_bounds__(256) void cheb_k(
    const int* __restrict__ rp, const int2* __restrict__ csr,
    const float* __restrict__ Tcur, const float* TprevBase, int tprevStride,
    float* Tnext, float* __restrict__ out,
    const float* __restrict__ w, int k, int goff) {
    int wid = blockIdx.x * 4 + (threadIdx.x >> 6);
    int r = __builtin_amdgcn_readfirstlane(wid);
    if (r >= N_NODES) return;
    int lane = threadIdx.x & 63;
    const float* base = Tcur + lane;          // gather Tcur[col*64 + lane]
    int e0 = rp[r], e1 = rp[r + 1];
    float a0 = 0.f, a1 = 0.f, a2 = 0.f, a3 = 0.f;
    int e = e0;
    for (; e + 4 <= e1; e += 4) {
        int2 cv0 = csr[e], cv1 = csr[e + 1], cv2 = csr[e + 2], cv3 = csr[e + 3];
        a0 = fmaf(__int_as_float(cv0.y), base[(size_t)cv0.x * GRP], a0);
        a1 = fmaf(__int_as_float(cv1.y), base[(size_t)cv1.x * GRP], a1);
        a2 = fmaf(__int_as_float(cv2.y), base[(size_t)cv2.x * GRP], a2);
        a3 = fmaf(__int_as_float(cv3.y), base[(size_t)cv3.x * GRP], a3);
    }
    for (; e < e1; ++e) {
        int2 cv = csr[e];
        a0 = fmaf(__int_as_float(cv.y), base[(size_t)cv.x * GRP], a0);
    }
    float s = (a0 + a1) + (a2 + a3);
    size_t idxg = (size_t)r * GRP + lane;
    size_t idxf = (size_t)r * H_CH + goff + lane;
    float tc = Tcur[idxg];
    float tp = TprevBase[(size_t)r * tprevStride + lane];
    float wk = w[k];
    float tn = 2.0f * (s - tc) - tp;
    float o = out[idxf];
    o -= wk * tn;
    out[idxf] = o;
    Tnext[idxg] = tn;
}

extern "C" void kernel_launch(void* const* d_in, const int* in_sizes, int n_in,
                              void* d_out, int out_size, void* d_ws, size_t ws_size,
                              hipStream_t stream) {
    const float* x      = (const float*)d_in[0];
    const float* vals   = (const float*)d_in[1];
    const float* logits = (const float*)d_in[2];
    const float* alpha  = (const float*)d_in[3];
    const int*   erow   = (const int*)d_in[4];
    const int*   ecol   = (const int*)d_in[5];
    float* out = (float*)d_out;

    const size_t NG = (size_t)N_NODES * GRP;       // per-group state elements
    float* bufA    = (float*)d_ws;                 // N x 64
    float* bufB    = bufA + NG;                    // N x 64
    int2*  csr     = (int2*)(bufB + NG);           // packed col+val, NNZ
    int*   row_ptr = (int*)(csr + NNZ_E);          // N+1
    int*   counts  = row_ptr + (N_NODES + 1);
    int*   fill    = counts + N_NODES;
    int*   partials= fill + N_NODES;               // 128 entries
    float* w_buf   = (float*)(partials + 128);     // 16 entries

    hipMemsetAsync(counts, 0, N_NODES * sizeof(int), stream);
    softmax_k<<<1, 64, 0, stream>>>(logits, w_buf);
    hist_k<<<(NNZ_E + 255) / 256, 256, 0, stream>>>(erow, counts, NNZ_E);

    const int TILE = 2048;
    int nblk = (N_NODES + TILE - 1) / TILE;        // 98
    scan1_k<<<nblk, 256, 0, stream>>>(counts, row_ptr, partials, N_NODES);
    scan2_k<<<1, 128, 0, stream>>>(partials, nblk, row_ptr, N_NODES, NNZ_E);
    scan3_k<<<nblk, 256, 0, stream>>>(row_ptr, partials, fill, N_NODES);
    scatter_k<<<(NNZ_E + 255) / 256, 256, 0, stream>>>(erow, ecol, vals, fill, csr, NNZ_E);

    int grid = (N_NODES + 3) / 4;                  // 4 rows (waves) per 256-thread block

    for (int g = 0; g < H_CH / GRP; ++g) {
        int goff = g * GRP;
        // T1 (compact) -> bufB; out slice initialized
        first_k<<<grid, 256, 0, stream>>>(row_ptr, csr, x, bufB, out, w_buf, alpha, goff);
        // k = 2: Tcur = T1 (bufB), Tprev = x slice (stride 128), Tnext -> bufA
        cheb_k<<<grid, 256, 0, stream>>>(row_ptr, csr, bufB, x + goff, H_CH, bufA,
                                         out, w_buf, 2, goff);
        // k = 3..15: ping-pong; Tnext aliases Tprev (read-before-write per thread)
        float* Tcur = bufA;
        float* Tprev = bufB;
        for (int k = 3; k <= K_DEG; ++k) {
            cheb_k<<<grid, 256, 0, stream>>>(row_ptr, csr, Tcur, Tprev, GRP, Tprev,
                                             out, w_buf, k, goff);
            float* t = Tcur; Tcur = Tprev; Tprev = t;
        }
    }
}